// Round 15
// baseline (352.516 us; speedup 1.0000x reference)
//
#include <hip/hip_runtime.h>
#include <hip/hip_bf16.h>
#include <math.h>

#define NBATCH 16
#define NW 64
#define WA 49
#define NTOK (NBATCH*NW*WA)   // 50176
#define CCH 384
#define HIDDEN 1536

typedef __attribute__((ext_vector_type(8))) short short8;
typedef __attribute__((ext_vector_type(4))) float floatx4;

static __device__ __forceinline__ short f2bf(float f){
  unsigned u = __float_as_uint(f);
  unsigned r = (u + 0x7fff + ((u>>16)&1)) >> 16;
  return (short)r;
}
static __device__ __forceinline__ float bf2f(short s){
  return __uint_as_float(((unsigned)(unsigned short)s)<<16);
}

static __device__ __forceinline__ void gload16(const void* g, void* l){
  __builtin_amdgcn_global_load_lds(
      (const __attribute__((address_space(1))) void*)g,
      (__attribute__((address_space(3))) void*)l, 16, 0, 0);
}

// opaque LDS reads: compiler cannot see global_load_lds -> ds_read dependence;
// we own the waitcnts (rule #18: lgkmcnt + sched_barrier before MFMA).
static __device__ __forceinline__ short8 ds_read_b128s(unsigned addr){
  short8 r;
  asm volatile("ds_read_b128 %0, %1" : "=v"(r) : "v"(addr));
  return r;
}
static __device__ __forceinline__ long ds_read_b64s(unsigned addr){
  long r;
  asm volatile("ds_read_b64 %0, %1" : "=v"(r) : "v"(addr));
  return r;
}

template<int N> __device__ __forceinline__ void waitvm();
template<> __device__ __forceinline__ void waitvm<0>(){ asm volatile("s_waitcnt vmcnt(0)" ::: "memory"); }
template<> __device__ __forceinline__ void waitvm<5>(){ asm volatile("s_waitcnt vmcnt(5)" ::: "memory"); }

// token index -> pixel index (same map for LN1 gather and proj scatter)
static __device__ __forceinline__ int tok2pix(int t){
  int b = t / (NW*WA);
  int rem = t % (NW*WA);
  int w = rem / WA, a = rem % WA;
  int hs = (w>>3)*7 + a/7;
  int ws = (w&7)*7 + a%7;
  int hp = hs + 3; if (hp >= 56) hp -= 56;
  int wp = ws + 3; if (wp >= 56) wp -= 56;
  return (b*56 + hp)*56 + wp;
}

// ---- weight transpose + fp32->bf16 convert: W[K,N] -> Wt[N,K] ----
__global__ void wtconv(const float* __restrict__ W, short* __restrict__ Wt, int K, int N){
  int i = blockIdx.x*256 + threadIdx.x;
  if (i >= K*N) return;
  int k = i / N, n = i % N;
  Wt[(size_t)n*K + k] = f2bf(W[i]);
}

// ---- weight transpose + fp32->fp8(e4m3) convert: W[K,N] -> Wt8[N,K] ----
__global__ void wtconv8(const float* __restrict__ W, unsigned char* __restrict__ Wt, int K, int N){
  int i = blockIdx.x*256 + threadIdx.x;
  if (i >= K*N) return;
  int k = i / N, n = i % N;
  unsigned pk = (unsigned)__builtin_amdgcn_cvt_pk_fp8_f32(W[i], W[i], 0, false);
  Wt[(size_t)n*K + k] = (unsigned char)(pk & 0xff);
}

// ---- rel_bias transpose: [169][12] -> [12][169] (coalesced lb staging) ----
__global__ void rbt(const float* __restrict__ rb, float* __restrict__ rbT){
  int i = blockIdx.x*256 + threadIdx.x;
  if (i >= 169*12) return;
  int t = i / 12, h = i % 12;
  rbT[h*169 + t] = rb[i];
}

// ---- LayerNorm emitting fp8 e4m3 (one wave per token, lanes 0-47 active).
// MAP=1: gather via tok2pix (LN1+shift+window)
template<int MAP>
__global__ __launch_bounds__(256) void ln_fp8(const float* __restrict__ x,
    const float* __restrict__ g, const float* __restrict__ bta, unsigned char* __restrict__ out){
  int wid = threadIdx.x>>6, lane = threadIdx.x&63;
  int t = blockIdx.x*4 + wid;
  const float* row = x + (size_t)(MAP ? tok2pix(t) : t)*CCH;
  float v[8]; float s=0.f, ss=0.f;
  if (lane < 48){
    float4 p0 = *(const float4*)&row[lane*8];
    float4 p1 = *(const float4*)&row[lane*8+4];
    v[0]=p0.x;v[1]=p0.y;v[2]=p0.z;v[3]=p0.w;
    v[4]=p1.x;v[5]=p1.y;v[6]=p1.z;v[7]=p1.w;
    #pragma unroll
    for (int i=0;i<8;i++){ s+=v[i]; ss+=v[i]*v[i]; }
  }
  #pragma unroll
  for (int off=32; off; off>>=1){ s += __shfl_xor(s,off); ss += __shfl_xor(ss,off); }
  float mean = s*(1.f/384.f);
  float var  = ss*(1.f/384.f) - mean*mean;
  float inv  = rsqrtf(var + 1e-5f);
  if (lane < 48){
    float4 g0 = *(const float4*)&g[lane*8],  g1 = *(const float4*)&g[lane*8+4];
    float4 b0 = *(const float4*)&bta[lane*8],b1 = *(const float4*)&bta[lane*8+4];
    float o[8];
    o[0]=(v[0]-mean)*inv*g0.x+b0.x; o[1]=(v[1]-mean)*inv*g0.y+b0.y;
    o[2]=(v[2]-mean)*inv*g0.z+b0.z; o[3]=(v[3]-mean)*inv*g0.w+b0.w;
    o[4]=(v[4]-mean)*inv*g1.x+b1.x; o[5]=(v[5]-mean)*inv*g1.y+b1.y;
    o[6]=(v[6]-mean)*inv*g1.z+b1.z; o[7]=(v[7]-mean)*inv*g1.w+b1.w;
    unsigned w0 = (unsigned)__builtin_amdgcn_cvt_pk_fp8_f32(o[0], o[1], 0, false);
    w0 = (unsigned)__builtin_amdgcn_cvt_pk_fp8_f32(o[2], o[3], (int)w0, true);
    unsigned w1 = (unsigned)__builtin_amdgcn_cvt_pk_fp8_f32(o[4], o[5], 0, false);
    w1 = (unsigned)__builtin_amdgcn_cvt_pk_fp8_f32(o[6], o[7], (int)w1, true);
    uint2 pk; pk.x = w0; pk.y = w1;
    *(uint2*)&out[(size_t)t*CCH + lane*8] = pk;
  }
}

// ---- 8-wave pipelined bf16 MFMA GEMM (proj only) w/ coalesced epilogue.
// BM=256, BN=64, BK=64, double-buffered, counted vmcnt(5), XOR-swizzled LDS.
// EPI 1: proj -> y[pix] = x[pix] + v
template<int EPI, int KK>
__global__ __launch_bounds__(512) void gemm8(const short* __restrict__ A,
    const short* __restrict__ Bt, const float* __restrict__ bias,
    const float* __restrict__ res, void* __restrict__ outp,
    int N, int gx)
{
  __shared__ short As[2][256][64];   // 64 KB (reused as C-tile in epilogue)
  __shared__ short Bs[2][64][64];    // 16 KB
  const int tid = threadIdx.x, lane = tid & 63, wid = tid >> 6;
  const int fr = lane & 15, fg = lane >> 4;
  const int wm = wid >> 1, wn = wid & 1;

  const int nwg = gridDim.x;
  const int q = nwg >> 3, r = nwg & 7;
  const int xcd = blockIdx.x & 7, pos = blockIdx.x >> 3;
  const int wgid = (xcd < r ? xcd*(q+1) : r*(q+1) + (xcd-r)*q) + pos;
  const int m0 = (wgid / gx) * 256, n0 = (wgid % gx) * 64;

  floatx4 acc[4][2];
  #pragma unroll
  for (int m=0;m<4;m++)
    #pragma unroll
    for (int n=0;n<2;n++) acc[m][n] = (floatx4){0.f,0.f,0.f,0.f};

  const int srow = tid >> 3;
  const int scol = ((tid & 7) ^ (srow & 7)) * 8;
  const short* gA = A  + (size_t)(m0 + srow) * KK + scol;
  const short* gB = Bt + (size_t)(n0 + srow) * KK + scol;
  constexpr int a64 = 64 * KK;
  short* aB = &As[0][wid*8][0];
  short* bB = &Bs[0][wid*8][0];
  constexpr int nt = KK >> 6;

  const unsigned aLds = (unsigned)(uintptr_t)&As[0][0][0];
  const unsigned bLds = (unsigned)(uintptr_t)&Bs[0][0][0];
  const unsigned rowOffA = (unsigned)((wm*64 + fr)*128);
  const unsigned rowOffB = (unsigned)((wn*32 + fr)*128);
  const unsigned pc0 = (unsigned)(((fg  ) ^ (fr&7))*16);
  const unsigned pc1 = (unsigned)(((4+fg) ^ (fr&7))*16);

#define STAGE(tt, bb) do{                                             \
    const int k0_ = (tt) << 6;                                        \
    short* a_ = aB + (bb)*256*64;                                     \
    short* b_ = bB + (bb)*64*64;                                      \
    gload16(gA + k0_,          a_);                                   \
    gload16(gA + k0_ +   a64,  a_ +  64*64);                          \
    gload16(gA + k0_ + 2*a64,  a_ + 128*64);                          \
    gload16(gA + k0_ + 3*a64,  a_ + 192*64);                          \
    gload16(gB + k0_,          b_);                                   \
  }while(0)

  STAGE(0, 0);
  #pragma unroll
  for (int t = 0; t < nt; ++t){
    const int buf = t & 1;
    if (t + 1 < nt){
      STAGE(t+1, buf^1);
      waitvm<5>();
    } else {
      waitvm<0>();
    }
    __builtin_amdgcn_s_barrier();
    const unsigned aoff = aLds + (unsigned)buf*32768u + rowOffA;
    const unsigned boff = bLds + (unsigned)buf*8192u  + rowOffB;
    #pragma unroll
    for (int kk=0; kk<2; ++kk){
      const unsigned pc = kk ? pc1 : pc0;
      short8 af[4], bq[2];
      #pragma unroll
      for (int m=0;m<4;m++) af[m] = ds_read_b128s(aoff + (unsigned)(m*2048) + pc);
      #pragma unroll
      for (int n=0;n<2;n++) bq[n] = ds_read_b128s(boff + (unsigned)(n*2048) + pc);
      asm volatile("s_waitcnt lgkmcnt(0)" ::: "memory");
      __builtin_amdgcn_sched_barrier(0);
      __builtin_amdgcn_s_setprio(1);
      #pragma unroll
      for (int m=0;m<4;m++)
        #pragma unroll
        for (int n=0;n<2;n++)
          acc[m][n] = __builtin_amdgcn_mfma_f32_16x16x32_bf16(af[m], bq[n], acc[m][n], 0,0,0);
      __builtin_amdgcn_s_setprio(0);
    }
    __builtin_amdgcn_s_barrier();
  }
#undef STAGE

  // ---- LDS-staged coalesced fp32 epilogue (proj): y[pix] = x[pix] + v ----
  __syncthreads();
  float* Cl = (float*)&As[0][0][0];  // [256][64] fp32 (64 KB)
  #pragma unroll
  for (int n=0;n<2;n++){
    int col = wn*32 + n*16 + fr;
    float bv = bias[n0 + col];
    #pragma unroll
    for (int m=0;m<4;m++){
      #pragma unroll
      for (int i=0;i<4;i++){
        int row = wm*64 + m*16 + fg*4 + i;
        Cl[row*64 + col] = acc[m][n][i] + bv;
      }
    }
  }
  __syncthreads();
  const int rr = tid >> 4, slot = tid & 15;
  #pragma unroll
  for (int it=0; it<8; ++it){
    int row = it*32 + rr;
    float4 v = *(const float4*)&Cl[row*64 + slot*4];
    int p = tok2pix(m0+row);
    size_t idx = (size_t)p*CCH + n0 + slot*4;
    float4 rv = *(const float4*)&res[idx];
    v.x += rv.x; v.y += rv.y; v.z += rv.z; v.w += rv.w;
    *(float4*)&((float*)outp)[idx] = v;
  }
}

// ---- fp8 x fp8 MFMA GEMM, BK=128 bytes (half the convoys of bf16 BK=64).
// BM=256, BN=64, 8 waves. 16B-granule XOR swizzle.
// EPI 0: store bf16 (qkv)   EPI 2: sigmoid-GELU -> fp8 (fc1)
// EPI 3: out[t] = res[t] + v + bias (fc2, fp32)
template<int EPI, int KK>
__global__ __launch_bounds__(512) void gemmF8(const unsigned char* __restrict__ A8,
    const unsigned char* __restrict__ B8, const float* __restrict__ bias,
    const float* __restrict__ res, void* __restrict__ outp,
    int N, int gx)
{
  __shared__ unsigned char As8[2][256][128];  // 64 KB (reused as C-tile)
  __shared__ unsigned char Bs8[2][64][128];   // 16 KB
  const int tid = threadIdx.x, lane = tid & 63, wid = tid >> 6;
  const int fr = lane & 15, fg = lane >> 4;
  const int wm = wid >> 1, wn = wid & 1;

  const int nwg = gridDim.x;
  const int q = nwg >> 3, r = nwg & 7;
  const int xcd = blockIdx.x & 7, pos = blockIdx.x >> 3;
  const int wgid = (xcd < r ? xcd*(q+1) : r*(q+1) + (xcd-r)*q) + pos;
  const int m0 = (wgid / gx) * 256, n0 = (wgid % gx) * 64;

  floatx4 acc[4][2];
  #pragma unroll
  for (int m=0;m<4;m++)
    #pragma unroll
    for (int n=0;n<2;n++) acc[m][n] = (floatx4){0.f,0.f,0.f,0.f};

  const int srow = tid >> 3;
  const int scolb = ((tid & 7) ^ (srow & 7)) * 16;   // byte offset, 16B granule
  const unsigned char* gA = A8 + (size_t)(m0 + srow) * KK + scolb;
  const unsigned char* gB = B8 + (size_t)(n0 + srow) * KK + scolb;
  constexpr int a64 = 64 * KK;                        // byte stride of 64 rows
  unsigned char* aB = &As8[0][wid*8][0];
  unsigned char* bB = &Bs8[0][wid*8][0];
  constexpr int nt = KK >> 7;                         // BK=128 bytes

  const unsigned aLds = (unsigned)(uintptr_t)&As8[0][0][0];
  const unsigned bLds = (unsigned)(uintptr_t)&Bs8[0][0][0];
  const unsigned rowOffA = (unsigned)((wm*64 + fr)*128);
  const unsigned rowOffB = (unsigned)((wn*32 + fr)*128);
  unsigned pcc[4];
  #pragma unroll
  for (int kk=0;kk<4;kk++)
    pcc[kk] = (unsigned)((((kk*2 + (fg>>1)) ^ (fr&7))*16) + (fg&1)*8);

#define STAGE8(tt, bb) do{                                            \
    const int k0_ = (tt) << 7;                                        \
    unsigned char* a_ = aB + (bb)*256*128;                            \
    unsigned char* b_ = bB + (bb)*64*128;                             \
    gload16(gA + k0_,          a_);                                   \
    gload16(gA + k0_ +   a64,  a_ +  8192);                           \
    gload16(gA + k0_ + 2*a64,  a_ + 16384);                           \
    gload16(gA + k0_ + 3*a64,  a_ + 24576);                           \
    gload16(gB + k0_,          b_);                                   \
  }while(0)

  STAGE8(0, 0);
  #pragma unroll
  for (int t = 0; t < nt; ++t){
    const int buf = t & 1;
    if (t + 1 < nt){
      STAGE8(t+1, buf^1);
      waitvm<5>();
    } else {
      waitvm<0>();
    }
    __builtin_amdgcn_s_barrier();
    const unsigned aoff = aLds + (unsigned)buf*32768u + rowOffA;
    const unsigned boff = bLds + (unsigned)buf*8192u  + rowOffB;
    #pragma unroll
    for (int kk=0; kk<4; ++kk){
      const unsigned pc = pcc[kk];
      long af[4], bq[2];
      #pragma unroll
      for (int m=0;m<4;m++) af[m] = ds_read_b64s(aoff + (unsigned)(m*2048) + pc);
      #pragma unroll
      for (int n=0;n<2;n++) bq[n] = ds_read_b64s(boff + (unsigned)(n*2048) + pc);
      asm volatile("s_waitcnt lgkmcnt(0)" ::: "memory");
      __builtin_amdgcn_sched_barrier(0);
      __builtin_amdgcn_s_setprio(1);
      #pragma unroll
      for (int m=0;m<4;m++)
        #pragma unroll
        for (int n=0;n<2;n++)
          acc[m][n] = __builtin_amdgcn_mfma_f32_16x16x32_fp8_fp8(af[m], bq[n], acc[m][n], 0,0,0);
      __builtin_amdgcn_s_setprio(0);
    }
    __builtin_amdgcn_s_barrier();
  }
#undef STAGE8

  // ---- LDS-staged coalesced epilogue ----
  __syncthreads();
  if (EPI==0){
    short* Cl = (short*)&As8[0][0][0];  // [256][64] bf16 (32 KB)
    #pragma unroll
    for (int n=0;n<2;n++){
      int col = wn*32 + n*16 + fr;
      float bv = bias[n0 + col];
      #pragma unroll
      for (int m=0;m<4;m++){
        #pragma unroll
        for (int i=0;i<4;i++){
          int row = wm*64 + m*16 + fg*4 + i;
          Cl[row*64 + col] = f2bf(acc[m][n][i] + bv);
        }
      }
    }
    __syncthreads();
    const int rr = tid >> 3, slot = tid & 7;
    #pragma unroll
    for (int it=0; it<4; ++it){
      int row = it*64 + rr;
      short8 v = *(const short8*)&Cl[row*64 + slot*8];
      *(short8*)&((short*)outp)[(size_t)(m0+row)*N + n0 + slot*8] = v;
    }
  } else if (EPI==2){
    unsigned char* Cl = (unsigned char*)&As8[0][0][0];  // [256][64] fp8
    #pragma unroll
    for (int n=0;n<2;n++){
      int col = wn*32 + n*16 + fr;
      float bv = bias[n0 + col];
      #pragma unroll
      for (int m=0;m<4;m++){
        #pragma unroll
        for (int i=0;i<4;i++){
          int row = wm*64 + m*16 + fg*4 + i;
          float v = acc[m][n][i] + bv;
          // sigmoid-GELU: v * sigma(1.702 v), inf-safe form
          float e2 = __expf(-1.702f*v);
          float gg = v * __builtin_amdgcn_rcpf(1.f + e2);
          unsigned pk = (unsigned)__builtin_amdgcn_cvt_pk_fp8_f32(gg, gg, 0, false);
          Cl[row*64 + col] = (unsigned char)(pk & 0xff);
        }
      }
    }
    __syncthreads();
    const int rr = tid >> 2, slot = tid & 3;
    #pragma unroll
    for (int it=0; it<2; ++it){
      int row = it*128 + rr;
      short8 v = *(const short8*)&Cl[row*64 + slot*16];
      *(short8*)&((unsigned char*)outp)[(size_t)(m0+row)*N + n0 + slot*16] = v;
    }
  } else {
    float* Cl = (float*)&As8[0][0][0];   // [256][64] fp32 (64 KB)
    #pragma unroll
    for (int n=0;n<2;n++){
      int col = wn*32 + n*16 + fr;
      float bv = bias[n0 + col];
      #pragma unroll
      for (int m=0;m<4;m++){
        #pragma unroll
        for (int i=0;i<4;i++){
          int row = wm*64 + m*16 + fg*4 + i;
          Cl[row*64 + col] = acc[m][n][i] + bv;
        }
      }
    }
    __syncthreads();
    const int rr = tid >> 4, slot = tid & 15;
    #pragma unroll
    for (int it=0; it<8; ++it){
      int row = it*32 + rr;
      float4 v = *(const float4*)&Cl[row*64 + slot*4];
      size_t idx = (size_t)(m0+row)*CCH + n0 + slot*4;
      float4 rv = *(const float4*)&res[idx];
      v.x += rv.x; v.y += rv.y; v.z += rv.z; v.w += rv.w;
      *(float4*)&((float*)outp)[idx] = v;
    }
  }
}

// ---- MFMA windowed attention: block = window, wave w -> heads w, w+4, w+8.
// ALL per-iteration barriers removed: Pl/Vt/lb are PER-WAVE LDS slices, so
// same-wave lgkmcnt ordering (compiler-inserted) is sufficient. Single block
// barrier after grp init (wave 0 writes grp, all waves read).
__global__ __launch_bounds__(256) void attn_mfma(const short* __restrict__ qkv,
    const float* __restrict__ rbT, short* __restrict__ attnout)
{
  __shared__ short Pl[4][64][68];
  __shared__ short Vt[4][32][68];
  __shared__ float lb[4][169];
  __shared__ int grp[64];
  const int wi = blockIdx.x;
  const int wid = threadIdx.x>>6, lane = threadIdx.x&63;
  const int fr = lane&15, fg = lane>>4;
  const int w = wi & 63, wh = w>>3, ww = w&7;
  if (threadIdx.x < 64){
    int t = threadIdx.x;
    int gv = 0;
    if (t < 49){
      int ai = t/7, aj = t%7;
      int hs = wh*7+ai, ws = ww*7+aj;
      int gh = hs<49?0:(hs<53?1:2);
      int gw = ws<49?0:(ws<53?1:2);
      gv = gh*3+gw;
    } else gv = -1;
    grp[t] = gv;
  }
  for (int t = lane; t < 32*15; t += 64){
    int d = t/15, j = 49 + t - d*15;
    Vt[wid][d][j] = 0;
  }
  __syncthreads();   // the ONLY block barrier: grp visible to all waves
  const size_t tbase = (size_t)wi*49;
  const float SCALE = 0.17677669529663687f;

  for (int hi=0; hi<3; ++hi){
    const int h = hi*4 + wid;
    // coalesced lb staging from pre-transposed rel_bias [12][169]
    for (int t = lane; t < 169; t += 64) lb[wid][t] = rbT[h*169 + t];
    for (int t = lane; t < 196; t += 64){
      int j = t>>2, d0 = (t&3)*8;
      short8 vv = *(const short8*)&qkv[(tbase+j)*1152 + 768 + h*32 + d0];
      #pragma unroll
      for (int s=0;s<8;s++) Vt[wid][d0+s][j] = vv[s];
    }
    short8 zf = {};
    short8 aq[4], bk[4];
    #pragma unroll
    for (int m=0;m<4;m++){
      int r = m*16+fr;
      aq[m] = (r<49) ? *(const short8*)&qkv[(tbase+r)*1152       + h*32 + fg*8] : zf;
      bk[m] = (r<49) ? *(const short8*)&qkv[(tbase+r)*1152 + 384 + h*32 + fg*8] : zf;
    }

    floatx4 sc[4][4];
    #pragma unroll
    for (int m=0;m<4;m++)
      #pragma unroll
      for (int n=0;n<4;n++)
        sc[m][n] = __builtin_amdgcn_mfma_f32_16x16x32_bf16(aq[m], bk[n], (floatx4){0.f,0.f,0.f,0.f}, 0,0,0);

    int ciC[4], cjC[4], gC[4], cvC[4];
    #pragma unroll
    for (int n=0;n<4;n++){
      int c = n*16+fr;
      ciC[n] = c/7; cjC[n] = c - ciC[n]*7;
      gC[n] = grp[c]; cvC[n] = (c<49);
    }
    #pragma unroll
    for (int m=0;m<4;m++){
      #pragma unroll
      for (int i=0;i<4;i++){
        int r = m*16 + fg*4 + i;
        int rv = (r<49);
        int ri = r/7, rj = r - ri*7;
        int gr = grp[r];
        float mxv = -3e30f;
        #pragma unroll
        for (int n=0;n<4;n++){
          float s;
          if (rv && cvC[n]){
            int dr = ri - ciC[n] + 6, dc = rj - cjC[n] + 6;
            s = sc[m][n][i]*SCALE + lb[wid][dr*13+dc];
            if (gr != gC[n]) s -= 100.f;
          } else s = -3e30f;
          sc[m][n][i] = s;
          mxv = fmaxf(mxv, s);
        }
        #pragma unroll
        for (int off=1;off<16;off<<=1) mxv = fmaxf(mxv, __shfl_xor(mxv, off));
        float sum = 0.f;
        #pragma unroll
        for (int n=0;n<4;n++){
          float e = __expf(sc[m][n][i]-mxv);
          sc[m][n][i] = e; sum += e;
        }
        #pragma unroll
        for (int off=1;off<16;off<<=1) sum += __shfl_xor(sum, off);
        float inv = 1.f/sum;
        #pragma unroll
        for (int n=0;n<4;n++)
          Pl[wid][r][n*16+fr] = f2bf(sc[m][n][i]*inv);
      }
    }

    short8 pa[4][2], vb[2][2];
    #pragma unroll
    for (int m=0;m<4;m++)
      #pragma unroll
      for (int ks=0;ks<2;ks++)
        pa[m][ks] = *(const short8*)&Pl[wid][m*16+fr][ks*32+fg*8];
    #pragma unroll
    for (int n2=0;n2<2;n2++)
      #pragma unroll
      for (int ks=0;ks<2;ks++)
        vb[n2][ks] = *(const short8*)&Vt[wid][n2*16+fr][ks*32+fg*8];
    floatx4 oc[4][2];
    #pragma unroll
    for (int m=0;m<4;m++)
      #pragma unroll
      for (int n2=0;n2<2;n2++){
        oc[m][n2] = (floatx4){0.f,0.f,0.f,0.f};
        #pragma unroll
        for (int ks=0;ks<2;ks++)
          oc[m][n2] = __builtin_amdgcn_mfma_f32_16x16x32_bf16(pa[m][ks], vb[n2][ks], oc[m][n2], 0,0,0);
      }
    #pragma unroll
    for (int m=0;m<4;m++){
      #pragma unroll
      for (int i=0;i<4;i++){
        int r = m*16 + fg*4 + i;
        if (r < 49){
          #pragma unroll
          for (int n2=0;n2<2;n2++)
            attnout[(tbase+r)*384 + h*32 + n2*16 + fr] = f2bf(oc[m][n2][i]);
        }
      }
    }
  }
}

extern "C" void kernel_launch(void* const* d_in, const int* in_sizes, int n_in,
                              void* d_out, int out_size, void* d_ws, size_t ws_size,
                              hipStream_t stream)
{
  const float* x      = (const float*)d_in[0];
  const float* n1g    = (const float*)d_in[1];
  const float* n1b    = (const float*)d_in[2];
  const float* qkv_w  = (const float*)d_in[3];
  const float* qkv_b  = (const float*)d_in[4];
  const float* relb   = (const float*)d_in[5];
  const float* proj_w = (const float*)d_in[6];
  const float* proj_b = (const float*)d_in[7];
  const float* n2g    = (const float*)d_in[8];
  const float* n2b    = (const float*)d_in[9];
  const float* fc1_w  = (const float*)d_in[10];
  const float* fc1_b  = (const float*)d_in[11];
  const float* fc2_w  = (const float*)d_in[12];
  const float* fc2_b  = (const float*)d_in[13];

  char* ws = (char*)d_ws;
  const size_t SZ_XW  = (size_t)NTOK*CCH*2;
  const size_t SZ_QKV = (size_t)NTOK*1152*2;
  const size_t SZ_ATT = SZ_XW;
  const size_t SZ_Y   = (size_t)NTOK*CCH*4;

  unsigned char* xw8 = (unsigned char*)(ws);             // [NTOK][384] fp8
  short* qkvb  = (short*)(ws + SZ_XW);                   // [NTOK][1152] bf16
  short* att   = (short*)(ws + SZ_XW + SZ_QKV);          // [NTOK][384] bf16
  float* y     = (float*)(ws + SZ_XW + SZ_QKV + SZ_ATT); // [NTOK][384] fp32
  char*  wbuf  = ws + SZ_XW + SZ_QKV + SZ_ATT + SZ_Y;
  unsigned char* qkvW8 = (unsigned char*)wbuf;                     // [1152][384] fp8
  short* projWt        = (short*)(qkvW8 + (size_t)1152*384);       // [384][384] bf16
  unsigned char* fc1W8 = (unsigned char*)(projWt + (size_t)384*384); // [1536][384] fp8
  unsigned char* fc2W8 = fc1W8 + (size_t)1536*384;                 // [384][1536] fp8
  float* rbT           = (float*)(fc2W8 + (size_t)384*1536);       // [12][169] fp32
  unsigned char* hbuf8 = (unsigned char*)qkvb;           // [NTOK][1536] fp8 (reuses qkv)
  unsigned char* hin8  = xw8;                            // [NTOK][384] fp8 (reuses xw)

  wtconv8<<<dim3((384*1152+255)/256), dim3(256), 0, stream>>>(qkv_w, qkvW8, 384, 1152);
  wtconv<<<dim3((384*384 +255)/256), dim3(256), 0, stream>>>(proj_w, projWt, 384, 384);
  wtconv8<<<dim3((384*1536+255)/256), dim3(256), 0, stream>>>(fc1_w, fc1W8, 384, 1536);
  wtconv8<<<dim3((1536*384+255)/256), dim3(256), 0, stream>>>(fc2_w, fc2W8, 1536, 384);
  rbt<<<dim3((169*12+255)/256), dim3(256), 0, stream>>>(relb, rbT);

  ln_fp8<1><<<dim3(NTOK/4), dim3(256), 0, stream>>>(x, n1g, n1b, xw8);
  gemmF8<0,384><<<dim3(18*196), dim3(512), 0, stream>>>(xw8, qkvW8, qkv_b, nullptr, qkvb, 1152, 18);
  attn_mfma<<<dim3(NBATCH*NW), dim3(256), 0, stream>>>(qkvb, rbT, att);
  gemm8<1,384><<<dim3(6*196),  dim3(512), 0, stream>>>(att, projWt, proj_b, x, y, 384, 6);
  ln_fp8<0><<<dim3(NTOK/4), dim3(256), 0, stream>>>(y, n2g, n2b, hin8);
  gemmF8<2,384><<<dim3(24*196), dim3(512), 0, stream>>>(hin8, fc1W8, fc1_b, nullptr, hbuf8, 1536, 24);
  gemmF8<3,1536><<<dim3(6*196), dim3(512), 0, stream>>>(hbuf8, fc2W8, fc2_b, y, (float*)d_out, 384, 6);
}

// Round 16
// 333.192 us; speedup vs baseline: 1.0580x; 1.0580x over previous
//
#include <hip/hip_runtime.h>
#include <hip/hip_bf16.h>
#include <math.h>

#define NBATCH 16
#define NW 64
#define WA 49
#define NTOK (NBATCH*NW*WA)   // 50176
#define CCH 384
#define HIDDEN 1536

typedef __attribute__((ext_vector_type(8))) short short8;
typedef __attribute__((ext_vector_type(4))) float floatx4;

static __device__ __forceinline__ short f2bf(float f){
  unsigned u = __float_as_uint(f);
  unsigned r = (u + 0x7fff + ((u>>16)&1)) >> 16;
  return (short)r;
}

static __device__ __forceinline__ void gload16(const void* g, void* l){
  __builtin_amdgcn_global_load_lds(
      (const __attribute__((address_space(1))) void*)g,
      (__attribute__((address_space(3))) void*)l, 16, 0, 0);
}

// opaque LDS read: we own the waitcnts (rule #18)
static __device__ __forceinline__ long ds_read_b64s(unsigned addr){
  long r;
  asm volatile("ds_read_b64 %0, %1" : "=v"(r) : "v"(addr));
  return r;
}

template<int N> __device__ __forceinline__ void waitvm();
template<> __device__ __forceinline__ void waitvm<0>(){ asm volatile("s_waitcnt vmcnt(0)" ::: "memory"); }
template<> __device__ __forceinline__ void waitvm<5>(){ asm volatile("s_waitcnt vmcnt(5)" ::: "memory"); }

// token index -> pixel index (same map for LN1 gather and proj scatter)
static __device__ __forceinline__ int tok2pix(int t){
  int b = t / (NW*WA);
  int rem = t % (NW*WA);
  int w = rem / WA, a = rem % WA;
  int hs = (w>>3)*7 + a/7;
  int ws = (w&7)*7 + a%7;
  int hp = hs + 3; if (hp >= 56) hp -= 56;
  int wp = ws + 3; if (wp >= 56) wp -= 56;
  return (b*56 + hp)*56 + wp;
}

// ---- weight transpose + fp32->fp8(e4m3) convert: W[K,N] -> Wt8[N,K] ----
__global__ void wtconv8(const float* __restrict__ W, unsigned char* __restrict__ Wt, int K, int N){
  int i = blockIdx.x*256 + threadIdx.x;
  if (i >= K*N) return;
  int k = i / N, n = i % N;
  unsigned pk = (unsigned)__builtin_amdgcn_cvt_pk_fp8_f32(W[i], W[i], 0, false);
  Wt[(size_t)n*K + k] = (unsigned char)(pk & 0xff);
}

// ---- rel_bias transpose: [169][12] -> [12][169] ----
__global__ void rbt(const float* __restrict__ rb, float* __restrict__ rbT){
  int i = blockIdx.x*256 + threadIdx.x;
  if (i >= 169*12) return;
  int t = i / 12, h = i % 12;
  rbT[h*169 + t] = rb[i];
}

// ---- LayerNorm emitting fp8 e4m3 (one wave per token, lanes 0-47 active).
template<int MAP>
__global__ __launch_bounds__(256) void ln_fp8(const float* __restrict__ x,
    const float* __restrict__ g, const float* __restrict__ bta, unsigned char* __restrict__ out){
  int wid = threadIdx.x>>6, lane = threadIdx.x&63;
  int t = blockIdx.x*4 + wid;
  const float* row = x + (size_t)(MAP ? tok2pix(t) : t)*CCH;
  float v[8]; float s=0.f, ss=0.f;
  if (lane < 48){
    float4 p0 = *(const float4*)&row[lane*8];
    float4 p1 = *(const float4*)&row[lane*8+4];
    v[0]=p0.x;v[1]=p0.y;v[2]=p0.z;v[3]=p0.w;
    v[4]=p1.x;v[5]=p1.y;v[6]=p1.z;v[7]=p1.w;
    #pragma unroll
    for (int i=0;i<8;i++){ s+=v[i]; ss+=v[i]*v[i]; }
  }
  #pragma unroll
  for (int off=32; off; off>>=1){ s += __shfl_xor(s,off); ss += __shfl_xor(ss,off); }
  float mean = s*(1.f/384.f);
  float var  = ss*(1.f/384.f) - mean*mean;
  float inv  = rsqrtf(var + 1e-5f);
  if (lane < 48){
    float4 g0 = *(const float4*)&g[lane*8],  g1 = *(const float4*)&g[lane*8+4];
    float4 b0 = *(const float4*)&bta[lane*8],b1 = *(const float4*)&bta[lane*8+4];
    float o[8];
    o[0]=(v[0]-mean)*inv*g0.x+b0.x; o[1]=(v[1]-mean)*inv*g0.y+b0.y;
    o[2]=(v[2]-mean)*inv*g0.z+b0.z; o[3]=(v[3]-mean)*inv*g0.w+b0.w;
    o[4]=(v[4]-mean)*inv*g1.x+b1.x; o[5]=(v[5]-mean)*inv*g1.y+b1.y;
    o[6]=(v[6]-mean)*inv*g1.z+b1.z; o[7]=(v[7]-mean)*inv*g1.w+b1.w;
    unsigned w0 = (unsigned)__builtin_amdgcn_cvt_pk_fp8_f32(o[0], o[1], 0, false);
    w0 = (unsigned)__builtin_amdgcn_cvt_pk_fp8_f32(o[2], o[3], (int)w0, true);
    unsigned w1 = (unsigned)__builtin_amdgcn_cvt_pk_fp8_f32(o[4], o[5], 0, false);
    w1 = (unsigned)__builtin_amdgcn_cvt_pk_fp8_f32(o[6], o[7], (int)w1, true);
    uint2 pk; pk.x = w0; pk.y = w1;
    *(uint2*)&out[(size_t)t*CCH + lane*8] = pk;
  }
}

// ---- fp8 x fp8 MFMA GEMM, BK=128 bytes. BM=256, BN=64, 8 waves.
// 16B-granule XOR swizzle (pre-swizzled global src; ds_read_b64 reads).
// EPI 2: sigmoid-GELU -> fp8 (fc1)
// EPI 3: out[t] = res[t] + v + bias (fc2, fp32)
// EPI 4: qkv -> fp8, Q columns (n0<384) pre-scaled by 1/sqrt(32)
// EPI 5: proj -> y[pix] = x[pix] + v + bias (fp32, tok2pix scatter)
template<int EPI, int KK>
__global__ __launch_bounds__(512) void gemmF8(const unsigned char* __restrict__ A8,
    const unsigned char* __restrict__ B8, const float* __restrict__ bias,
    const float* __restrict__ res, void* __restrict__ outp,
    int N, int gx)
{
  __shared__ unsigned char As8[2][256][128];  // 64 KB (reused as C-tile)
  __shared__ unsigned char Bs8[2][64][128];   // 16 KB
  const int tid = threadIdx.x, lane = tid & 63, wid = tid >> 6;
  const int fr = lane & 15, fg = lane >> 4;
  const int wm = wid >> 1, wn = wid & 1;

  const int nwg = gridDim.x;
  const int q = nwg >> 3, r = nwg & 7;
  const int xcd = blockIdx.x & 7, pos = blockIdx.x >> 3;
  const int wgid = (xcd < r ? xcd*(q+1) : r*(q+1) + (xcd-r)*q) + pos;
  const int m0 = (wgid / gx) * 256, n0 = (wgid % gx) * 64;

  floatx4 acc[4][2];
  #pragma unroll
  for (int m=0;m<4;m++)
    #pragma unroll
    for (int n=0;n<2;n++) acc[m][n] = (floatx4){0.f,0.f,0.f,0.f};

  const int srow = tid >> 3;
  const int scolb = ((tid & 7) ^ (srow & 7)) * 16;   // byte offset, 16B granule
  const unsigned char* gA = A8 + (size_t)(m0 + srow) * KK + scolb;
  const unsigned char* gB = B8 + (size_t)(n0 + srow) * KK + scolb;
  constexpr int a64 = 64 * KK;                        // byte stride of 64 rows
  unsigned char* aB = &As8[0][wid*8][0];
  unsigned char* bB = &Bs8[0][wid*8][0];
  constexpr int nt = KK >> 7;                         // BK=128 bytes

  const unsigned aLds = (unsigned)(uintptr_t)&As8[0][0][0];
  const unsigned bLds = (unsigned)(uintptr_t)&Bs8[0][0][0];
  const unsigned rowOffA = (unsigned)((wm*64 + fr)*128);
  const unsigned rowOffB = (unsigned)((wn*32 + fr)*128);
  unsigned pcc[4];
  #pragma unroll
  for (int kk=0;kk<4;kk++)
    pcc[kk] = (unsigned)((((kk*2 + (fg>>1)) ^ (fr&7))*16) + (fg&1)*8);

#define STAGE8(tt, bb) do{                                            \
    const int k0_ = (tt) << 7;                                        \
    unsigned char* a_ = aB + (bb)*256*128;                            \
    unsigned char* b_ = bB + (bb)*64*128;                             \
    gload16(gA + k0_,          a_);                                   \
    gload16(gA + k0_ +   a64,  a_ +  8192);                           \
    gload16(gA + k0_ + 2*a64,  a_ + 16384);                           \
    gload16(gA + k0_ + 3*a64,  a_ + 24576);                           \
    gload16(gB + k0_,          b_);                                   \
  }while(0)

  STAGE8(0, 0);
  #pragma unroll
  for (int t = 0; t < nt; ++t){
    const int buf = t & 1;
    if (t + 1 < nt){
      STAGE8(t+1, buf^1);
      waitvm<5>();
    } else {
      waitvm<0>();
    }
    __builtin_amdgcn_s_barrier();
    const unsigned aoff = aLds + (unsigned)buf*32768u + rowOffA;
    const unsigned boff = bLds + (unsigned)buf*8192u  + rowOffB;
    #pragma unroll
    for (int kk=0; kk<4; ++kk){
      const unsigned pc = pcc[kk];
      long af[4], bq[2];
      #pragma unroll
      for (int m=0;m<4;m++) af[m] = ds_read_b64s(aoff + (unsigned)(m*2048) + pc);
      #pragma unroll
      for (int n=0;n<2;n++) bq[n] = ds_read_b64s(boff + (unsigned)(n*2048) + pc);
      asm volatile("s_waitcnt lgkmcnt(0)" ::: "memory");
      __builtin_amdgcn_sched_barrier(0);
      __builtin_amdgcn_s_setprio(1);
      #pragma unroll
      for (int m=0;m<4;m++)
        #pragma unroll
        for (int n=0;n<2;n++)
          acc[m][n] = __builtin_amdgcn_mfma_f32_16x16x32_fp8_fp8(af[m], bq[n], acc[m][n], 0,0,0);
      __builtin_amdgcn_s_setprio(0);
    }
    __builtin_amdgcn_s_barrier();
  }
#undef STAGE8

  // ---- LDS-staged coalesced epilogue ----
  __syncthreads();
  if (EPI==2 || EPI==4){
    unsigned char* Cl = (unsigned char*)&As8[0][0][0];  // [256][64] fp8
    const float qscale = (EPI==4 && n0 < 384) ? 0.17677669529663687f : 1.f;
    #pragma unroll
    for (int n=0;n<2;n++){
      int col = wn*32 + n*16 + fr;
      float bv = bias[n0 + col];
      #pragma unroll
      for (int m=0;m<4;m++){
        #pragma unroll
        for (int i=0;i<4;i++){
          int row = wm*64 + m*16 + fg*4 + i;
          float v = acc[m][n][i] + bv;
          if (EPI==2){
            float e2 = __expf(-1.702f*v);
            v = v * __builtin_amdgcn_rcpf(1.f + e2);
          } else {
            v *= qscale;
          }
          unsigned pk = (unsigned)__builtin_amdgcn_cvt_pk_fp8_f32(v, v, 0, false);
          Cl[row*64 + col] = (unsigned char)(pk & 0xff);
        }
      }
    }
    __syncthreads();
    const int rr = tid >> 2, slot = tid & 3;
    #pragma unroll
    for (int it=0; it<2; ++it){
      int row = it*128 + rr;
      short8 v = *(const short8*)&Cl[row*64 + slot*16];
      *(short8*)&((unsigned char*)outp)[(size_t)(m0+row)*N + n0 + slot*16] = v;
    }
  } else {
    float* Cl = (float*)&As8[0][0][0];   // [256][64] fp32 (64 KB)
    #pragma unroll
    for (int n=0;n<2;n++){
      int col = wn*32 + n*16 + fr;
      float bv = bias[n0 + col];
      #pragma unroll
      for (int m=0;m<4;m++){
        #pragma unroll
        for (int i=0;i<4;i++){
          int row = wm*64 + m*16 + fg*4 + i;
          Cl[row*64 + col] = acc[m][n][i] + bv;
        }
      }
    }
    __syncthreads();
    const int rr = tid >> 4, slot = tid & 15;
    #pragma unroll
    for (int it=0; it<8; ++it){
      int row = it*32 + rr;
      float4 v = *(const float4*)&Cl[row*64 + slot*4];
      size_t idx;
      if (EPI==5){
        int p = tok2pix(m0+row);
        idx = (size_t)p*CCH + n0 + slot*4;
      } else {
        idx = (size_t)(m0+row)*CCH + n0 + slot*4;
      }
      float4 rv = *(const float4*)&res[idx];
      v.x += rv.x; v.y += rv.y; v.z += rv.z; v.w += rv.w;
      *(float4*)&((float*)outp)[idx] = v;
    }
  }
}

// ---- all-fp8 MFMA windowed attention: block = window, wave w -> heads w,w+4,w+8.
// Q pre-scaled at qkv epilogue (no SCALE mul here). QK^T and P*V via fp8 MFMA.
// Pl/Vt/lb are per-wave LDS slices -> single block barrier after grp init.
__global__ __launch_bounds__(256) void attn_mfma8(const unsigned char* __restrict__ qkv8,
    const float* __restrict__ rbT, unsigned char* __restrict__ att8)
{
  __shared__ unsigned char Pl[4][64][72];
  __shared__ unsigned char Vt[4][32][72];
  __shared__ float lb[4][169];
  __shared__ int grp[64];
  const int wi = blockIdx.x;
  const int wid = threadIdx.x>>6, lane = threadIdx.x&63;
  const int fr = lane&15, fg = lane>>4;
  const int w = wi & 63, wh = w>>3, ww = w&7;
  if (threadIdx.x < 64){
    int t = threadIdx.x;
    int gv = 0;
    if (t < 49){
      int ai = t/7, aj = t%7;
      int hs = wh*7+ai, ws = ww*7+aj;
      int gh = hs<49?0:(hs<53?1:2);
      int gw = ws<49?0:(ws<53?1:2);
      gv = gh*3+gw;
    } else gv = -1;
    grp[t] = gv;
  }
  // zero the whole Vt slice (covers j-padding 49..71); V stage overwrites j<49
  for (int t = lane; t < 288; t += 64)
    ((long*)&Vt[wid][0][0])[t] = 0;
  __syncthreads();   // the ONLY block barrier: grp visible to all waves
  const size_t tbase = (size_t)wi*49;

  for (int hi=0; hi<3; ++hi){
    const int h = hi*4 + wid;
    for (int t = lane; t < 169; t += 64) lb[wid][t] = rbT[h*169 + t];
    // stage V transposed (fp8 bytes): Vt[d][j] = V[j][d]
    for (int t = lane; t < 196; t += 64){
      int j = t>>2, d0 = (t&3)*8;
      unsigned long vv = *(const unsigned long*)&qkv8[(tbase+j)*1152 + 768 + h*32 + d0];
      #pragma unroll
      for (int s=0;s<8;s++) Vt[wid][d0+s][j] = (unsigned char)(vv >> (8*s));
    }
    long aq[4], bk[4];
    #pragma unroll
    for (int m=0;m<4;m++){
      int r = m*16+fr;
      aq[m] = (r<49) ? *(const long*)&qkv8[(tbase+r)*1152       + h*32 + fg*8] : 0L;
      bk[m] = (r<49) ? *(const long*)&qkv8[(tbase+r)*1152 + 384 + h*32 + fg*8] : 0L;
    }

    floatx4 sc[4][4];
    #pragma unroll
    for (int m=0;m<4;m++)
      #pragma unroll
      for (int n=0;n<4;n++)
        sc[m][n] = __builtin_amdgcn_mfma_f32_16x16x32_fp8_fp8(aq[m], bk[n], (floatx4){0.f,0.f,0.f,0.f}, 0,0,0);

    int ciC[4], cjC[4], gC[4], cvC[4];
    #pragma unroll
    for (int n=0;n<4;n++){
      int c = n*16+fr;
      ciC[n] = c/7; cjC[n] = c - ciC[n]*7;
      gC[n] = grp[c]; cvC[n] = (c<49);
    }
    #pragma unroll
    for (int m=0;m<4;m++){
      #pragma unroll
      for (int i=0;i<4;i++){
        int r = m*16 + fg*4 + i;
        int rv = (r<49);
        int ri = r/7, rj = r - ri*7;
        int gr = grp[r];
        float mxv = -3e30f;
        #pragma unroll
        for (int n=0;n<4;n++){
          float s;
          if (rv && cvC[n]){
            int dr = ri - ciC[n] + 6, dc = rj - cjC[n] + 6;
            s = sc[m][n][i] + lb[wid][dr*13+dc];
            if (gr != gC[n]) s -= 100.f;
          } else s = -3e30f;
          sc[m][n][i] = s;
          mxv = fmaxf(mxv, s);
        }
        #pragma unroll
        for (int off=1;off<16;off<<=1) mxv = fmaxf(mxv, __shfl_xor(mxv, off));
        float sum = 0.f;
        #pragma unroll
        for (int n=0;n<4;n++){
          float e = __expf(sc[m][n][i]-mxv);
          sc[m][n][i] = e; sum += e;
        }
        #pragma unroll
        for (int off=1;off<16;off<<=1) sum += __shfl_xor(sum, off);
        float inv = 1.f/sum;
        #pragma unroll
        for (int n=0;n<4;n++){
          float p = sc[m][n][i]*inv;
          unsigned pk = (unsigned)__builtin_amdgcn_cvt_pk_fp8_f32(p, p, 0, false);
          Pl[wid][r][n*16+fr] = (unsigned char)(pk & 0xff);
        }
      }
    }

    long pa[4][2], vb[2][2];
    #pragma unroll
    for (int m=0;m<4;m++)
      #pragma unroll
      for (int ks=0;ks<2;ks++)
        pa[m][ks] = *(const long*)&Pl[wid][m*16+fr][ks*32+fg*8];
    #pragma unroll
    for (int n2=0;n2<2;n2++)
      #pragma unroll
      for (int ks=0;ks<2;ks++)
        vb[n2][ks] = *(const long*)&Vt[wid][n2*16+fr][ks*32+fg*8];
    floatx4 oc[4][2];
    #pragma unroll
    for (int m=0;m<4;m++)
      #pragma unroll
      for (int n2=0;n2<2;n2++){
        oc[m][n2] = (floatx4){0.f,0.f,0.f,0.f};
        #pragma unroll
        for (int ks=0;ks<2;ks++)
          oc[m][n2] = __builtin_amdgcn_mfma_f32_16x16x32_fp8_fp8(pa[m][ks], vb[n2][ks], oc[m][n2], 0,0,0);
      }
    #pragma unroll
    for (int m=0;m<4;m++){
      #pragma unroll
      for (int i=0;i<4;i++){
        int r = m*16 + fg*4 + i;
        if (r < 49){
          #pragma unroll
          for (int n2=0;n2<2;n2++){
            float v = oc[m][n2][i];
            unsigned pk = (unsigned)__builtin_amdgcn_cvt_pk_fp8_f32(v, v, 0, false);
            att8[(tbase+r)*384 + h*32 + n2*16 + fr] = (unsigned char)(pk & 0xff);
          }
        }
      }
    }
  }
}

extern "C" void kernel_launch(void* const* d_in, const int* in_sizes, int n_in,
                              void* d_out, int out_size, void* d_ws, size_t ws_size,
                              hipStream_t stream)
{
  const float* x      = (const float*)d_in[0];
  const float* n1g    = (const float*)d_in[1];
  const float* n1b    = (const float*)d_in[2];
  const float* qkv_w  = (const float*)d_in[3];
  const float* qkv_b  = (const float*)d_in[4];
  const float* relb   = (const float*)d_in[5];
  const float* proj_w = (const float*)d_in[6];
  const float* proj_b = (const float*)d_in[7];
  const float* n2g    = (const float*)d_in[8];
  const float* n2b    = (const float*)d_in[9];
  const float* fc1_w  = (const float*)d_in[10];
  const float* fc1_b  = (const float*)d_in[11];
  const float* fc2_w  = (const float*)d_in[12];
  const float* fc2_b  = (const float*)d_in[13];

  char* ws = (char*)d_ws;
  const size_t SZ_XW  = (size_t)NTOK*CCH*2;
  const size_t SZ_QKV = (size_t)NTOK*1152*2;
  const size_t SZ_ATT = SZ_XW;
  const size_t SZ_Y   = (size_t)NTOK*CCH*4;

  unsigned char* xw8  = (unsigned char*)(ws);            // [NTOK][384] fp8
  unsigned char* qkv8 = (unsigned char*)(ws + SZ_XW);    // [NTOK][1152] fp8
  unsigned char* att8 = (unsigned char*)(ws + SZ_XW + SZ_QKV);  // [NTOK][384] fp8
  float* y     = (float*)(ws + SZ_XW + SZ_QKV + SZ_ATT); // [NTOK][384] fp32
  char*  wbuf  = ws + SZ_XW + SZ_QKV + SZ_ATT + SZ_Y;
  unsigned char* qkvW8 = (unsigned char*)wbuf;                     // [1152][384] fp8
  unsigned char* projW8= qkvW8 + (size_t)1152*384;                 // [384][384] fp8
  unsigned char* fc1W8 = projW8 + (size_t)384*384;                 // [1536][384] fp8
  unsigned char* fc2W8 = fc1W8 + (size_t)1536*384;                 // [384][1536] fp8
  float* rbT           = (float*)(fc2W8 + (size_t)384*1536);       // [12][169] fp32
  unsigned char* hbuf8 = qkv8;                           // [NTOK][1536] fp8 (reuses qkv8)
  unsigned char* hin8  = xw8;                            // [NTOK][384] fp8 (reuses xw8)

  wtconv8<<<dim3((384*1152+255)/256), dim3(256), 0, stream>>>(qkv_w, qkvW8, 384, 1152);
  wtconv8<<<dim3((384*384 +255)/256), dim3(256), 0, stream>>>(proj_w, projW8, 384, 384);
  wtconv8<<<dim3((384*1536+255)/256), dim3(256), 0, stream>>>(fc1_w, fc1W8, 384, 1536);
  wtconv8<<<dim3((1536*384+255)/256), dim3(256), 0, stream>>>(fc2_w, fc2W8, 1536, 384);
  rbt<<<dim3((169*12+255)/256), dim3(256), 0, stream>>>(relb, rbT);

  ln_fp8<1><<<dim3(NTOK/4), dim3(256), 0, stream>>>(x, n1g, n1b, xw8);
  gemmF8<4,384><<<dim3(18*196), dim3(512), 0, stream>>>(xw8, qkvW8, qkv_b, nullptr, qkv8, 1152, 18);
  attn_mfma8<<<dim3(NBATCH*NW), dim3(256), 0, stream>>>(qkv8, rbT, att8);
  gemmF8<5,384><<<dim3(6*196),  dim3(512), 0, stream>>>(att8, projW8, proj_b, x, y, 384, 6);
  ln_fp8<0><<<dim3(NTOK/4), dim3(256), 0, stream>>>(y, n2g, n2b, hin8);
  gemmF8<2,384><<<dim3(24*196), dim3(512), 0, stream>>>(hin8, fc1W8, fc1_b, nullptr, hbuf8, 1536, 24);
  gemmF8<3,1536><<<dim3(6*196), dim3(512), 0, stream>>>(hbuf8, fc2W8, fc2_b, y, (float*)d_out, 384, 6);
}

// Round 17
// 315.531 us; speedup vs baseline: 1.1172x; 1.0560x over previous
//
#include <hip/hip_runtime.h>
#include <hip/hip_bf16.h>
#include <math.h>

#define NBATCH 16
#define NW 64
#define WA 49
#define NTOK (NBATCH*NW*WA)   // 50176
#define CCH 384
#define HIDDEN 1536

typedef __attribute__((ext_vector_type(8))) short short8;
typedef __attribute__((ext_vector_type(4))) float floatx4;

static __device__ __forceinline__ short f2bf(float f){
  unsigned u = __float_as_uint(f);
  unsigned r = (u + 0x7fff + ((u>>16)&1)) >> 16;
  return (short)r;
}
static __device__ __forceinline__ float bf2f(short s){
  return __uint_as_float(((unsigned)(unsigned short)s)<<16);
}

static __device__ __forceinline__ void gload16(const void* g, void* l){
  __builtin_amdgcn_global_load_lds(
      (const __attribute__((address_space(1))) void*)g,
      (__attribute__((address_space(3))) void*)l, 16, 0, 0);
}

// opaque LDS read: we own the waitcnts (rule #18)
static __device__ __forceinline__ long ds_read_b64s(unsigned addr){
  long r;
  asm volatile("ds_read_b64 %0, %1" : "=v"(r) : "v"(addr));
  return r;
}

template<int N> __device__ __forceinline__ void waitvm();
template<> __device__ __forceinline__ void waitvm<0>(){ asm volatile("s_waitcnt vmcnt(0)" ::: "memory"); }
template<> __device__ __forceinline__ void waitvm<5>(){ asm volatile("s_waitcnt vmcnt(5)" ::: "memory"); }

// token index -> pixel index (same map for LN1 gather and proj scatter)
static __device__ __forceinline__ int tok2pix(int t){
  int b = t / (NW*WA);
  int rem = t % (NW*WA);
  int w = rem / WA, a = rem % WA;
  int hs = (w>>3)*7 + a/7;
  int ws = (w&7)*7 + a%7;
  int hp = hs + 3; if (hp >= 56) hp -= 56;
  int wp = ws + 3; if (wp >= 56) wp -= 56;
  return (b*56 + hp)*56 + wp;
}

// ---- weight transpose + fp32->fp8(e4m3) convert: W[K,N] -> Wt8[N,K] ----
__global__ void wtconv8(const float* __restrict__ W, unsigned char* __restrict__ Wt, int K, int N){
  int i = blockIdx.x*256 + threadIdx.x;
  if (i >= K*N) return;
  int k = i / N, n = i % N;
  unsigned pk = (unsigned)__builtin_amdgcn_cvt_pk_fp8_f32(W[i], W[i], 0, false);
  Wt[(size_t)n*K + k] = (unsigned char)(pk & 0xff);
}

// ---- rel_bias transpose: [169][12] -> [12][169] ----
__global__ void rbt(const float* __restrict__ rb, float* __restrict__ rbT){
  int i = blockIdx.x*256 + threadIdx.x;
  if (i >= 169*12) return;
  int t = i / 12, h = i % 12;
  rbT[h*169 + t] = rb[i];
}

// ---- LayerNorm emitting fp8 e4m3 (one wave per token, lanes 0-47 active).
// MAP=1: gather via tok2pix. BF=1: input rows are bf16 (else fp32).
template<int MAP, int BF>
__global__ __launch_bounds__(256) void ln_fp8(const void* __restrict__ xv,
    const float* __restrict__ g, const float* __restrict__ bta, unsigned char* __restrict__ out){
  int wid = threadIdx.x>>6, lane = threadIdx.x&63;
  int t = blockIdx.x*4 + wid;
  const size_t roff = (size_t)(MAP ? tok2pix(t) : t)*CCH;
  float v[8]; float s=0.f, ss=0.f;
  if (lane < 48){
    if (BF){
      const short* row = (const short*)xv + roff;
      short8 p = *(const short8*)&row[lane*8];
      #pragma unroll
      for (int i=0;i<8;i++) v[i] = bf2f(p[i]);
    } else {
      const float* row = (const float*)xv + roff;
      float4 p0 = *(const float4*)&row[lane*8];
      float4 p1 = *(const float4*)&row[lane*8+4];
      v[0]=p0.x;v[1]=p0.y;v[2]=p0.z;v[3]=p0.w;
      v[4]=p1.x;v[5]=p1.y;v[6]=p1.z;v[7]=p1.w;
    }
    #pragma unroll
    for (int i=0;i<8;i++){ s+=v[i]; ss+=v[i]*v[i]; }
  }
  #pragma unroll
  for (int off=32; off; off>>=1){ s += __shfl_xor(s,off); ss += __shfl_xor(ss,off); }
  float mean = s*(1.f/384.f);
  float var  = ss*(1.f/384.f) - mean*mean;
  float inv  = rsqrtf(var + 1e-5f);
  if (lane < 48){
    float4 g0 = *(const float4*)&g[lane*8],  g1 = *(const float4*)&g[lane*8+4];
    float4 b0 = *(const float4*)&bta[lane*8],b1 = *(const float4*)&bta[lane*8+4];
    float o[8];
    o[0]=(v[0]-mean)*inv*g0.x+b0.x; o[1]=(v[1]-mean)*inv*g0.y+b0.y;
    o[2]=(v[2]-mean)*inv*g0.z+b0.z; o[3]=(v[3]-mean)*inv*g0.w+b0.w;
    o[4]=(v[4]-mean)*inv*g1.x+b1.x; o[5]=(v[5]-mean)*inv*g1.y+b1.y;
    o[6]=(v[6]-mean)*inv*g1.z+b1.z; o[7]=(v[7]-mean)*inv*g1.w+b1.w;
    unsigned w0 = (unsigned)__builtin_amdgcn_cvt_pk_fp8_f32(o[0], o[1], 0, false);
    w0 = (unsigned)__builtin_amdgcn_cvt_pk_fp8_f32(o[2], o[3], (int)w0, true);
    unsigned w1 = (unsigned)__builtin_amdgcn_cvt_pk_fp8_f32(o[4], o[5], 0, false);
    w1 = (unsigned)__builtin_amdgcn_cvt_pk_fp8_f32(o[6], o[7], (int)w1, true);
    uint2 pk; pk.x = w0; pk.y = w1;
    *(uint2*)&out[(size_t)t*CCH + lane*8] = pk;
  }
}

// ---- fp8 x fp8 MFMA GEMM, BK=128 bytes. BM=256, BN=64, 8 waves.
// 16B-granule XOR swizzle (pre-swizzled global src; ds_read_b64 reads).
// EPI 2: sigmoid-GELU -> fp8 (fc1)
// EPI 3: out[t] = res_bf16[t] + v + bias (fc2, fp32 out)
// EPI 4: qkv -> fp8, Q columns (n0<384) pre-scaled by 1/sqrt(32)
// EPI 5: proj -> y_bf16[pix] = x_fp32[pix] + v + bias
template<int EPI, int KK>
__global__ __launch_bounds__(512) void gemmF8(const unsigned char* __restrict__ A8,
    const unsigned char* __restrict__ B8, const float* __restrict__ bias,
    const void* __restrict__ resv, void* __restrict__ outp,
    int N, int gx)
{
  __shared__ unsigned char As8[2][256][128];  // 64 KB (reused as C-tile)
  __shared__ unsigned char Bs8[2][64][128];   // 16 KB
  const int tid = threadIdx.x, lane = tid & 63, wid = tid >> 6;
  const int fr = lane & 15, fg = lane >> 4;
  const int wm = wid >> 1, wn = wid & 1;

  const int nwg = gridDim.x;
  const int q = nwg >> 3, r = nwg & 7;
  const int xcd = blockIdx.x & 7, pos = blockIdx.x >> 3;
  const int wgid = (xcd < r ? xcd*(q+1) : r*(q+1) + (xcd-r)*q) + pos;
  const int m0 = (wgid / gx) * 256, n0 = (wgid % gx) * 64;

  floatx4 acc[4][2];
  #pragma unroll
  for (int m=0;m<4;m++)
    #pragma unroll
    for (int n=0;n<2;n++) acc[m][n] = (floatx4){0.f,0.f,0.f,0.f};

  const int srow = tid >> 3;
  const int scolb = ((tid & 7) ^ (srow & 7)) * 16;   // byte offset, 16B granule
  const unsigned char* gA = A8 + (size_t)(m0 + srow) * KK + scolb;
  const unsigned char* gB = B8 + (size_t)(n0 + srow) * KK + scolb;
  constexpr int a64 = 64 * KK;                        // byte stride of 64 rows
  unsigned char* aB = &As8[0][wid*8][0];
  unsigned char* bB = &Bs8[0][wid*8][0];
  constexpr int nt = KK >> 7;                         // BK=128 bytes

  const unsigned aLds = (unsigned)(uintptr_t)&As8[0][0][0];
  const unsigned bLds = (unsigned)(uintptr_t)&Bs8[0][0][0];
  const unsigned rowOffA = (unsigned)((wm*64 + fr)*128);
  const unsigned rowOffB = (unsigned)((wn*32 + fr)*128);
  unsigned pcc[4];
  #pragma unroll
  for (int kk=0;kk<4;kk++)
    pcc[kk] = (unsigned)((((kk*2 + (fg>>1)) ^ (fr&7))*16) + (fg&1)*8);

#define STAGE8(tt, bb) do{                                            \
    const int k0_ = (tt) << 7;                                        \
    unsigned char* a_ = aB + (bb)*256*128;                            \
    unsigned char* b_ = bB + (bb)*64*128;                             \
    gload16(gA + k0_,          a_);                                   \
    gload16(gA + k0_ +   a64,  a_ +  8192);                           \
    gload16(gA + k0_ + 2*a64,  a_ + 16384);                           \
    gload16(gA + k0_ + 3*a64,  a_ + 24576);                           \
    gload16(gB + k0_,          b_);                                   \
  }while(0)

  STAGE8(0, 0);
  #pragma unroll
  for (int t = 0; t < nt; ++t){
    const int buf = t & 1;
    if (t + 1 < nt){
      STAGE8(t+1, buf^1);
      waitvm<5>();
    } else {
      waitvm<0>();
    }
    __builtin_amdgcn_s_barrier();
    const unsigned aoff = aLds + (unsigned)buf*32768u + rowOffA;
    const unsigned boff = bLds + (unsigned)buf*8192u  + rowOffB;
    #pragma unroll
    for (int kk=0; kk<4; ++kk){
      const unsigned pc = pcc[kk];
      long af[4], bq[2];
      #pragma unroll
      for (int m=0;m<4;m++) af[m] = ds_read_b64s(aoff + (unsigned)(m*2048) + pc);
      #pragma unroll
      for (int n=0;n<2;n++) bq[n] = ds_read_b64s(boff + (unsigned)(n*2048) + pc);
      asm volatile("s_waitcnt lgkmcnt(0)" ::: "memory");
      __builtin_amdgcn_sched_barrier(0);
      __builtin_amdgcn_s_setprio(1);
      #pragma unroll
      for (int m=0;m<4;m++)
        #pragma unroll
        for (int n=0;n<2;n++)
          acc[m][n] = __builtin_amdgcn_mfma_f32_16x16x32_fp8_fp8(af[m], bq[n], acc[m][n], 0,0,0);
      __builtin_amdgcn_s_setprio(0);
    }
    __builtin_amdgcn_s_barrier();
  }
#undef STAGE8

  // ---- LDS-staged coalesced epilogue ----
  __syncthreads();
  if (EPI==2 || EPI==4){
    unsigned char* Cl = (unsigned char*)&As8[0][0][0];  // [256][64] fp8
    const float qscale = (EPI==4 && n0 < 384) ? 0.17677669529663687f : 1.f;
    #pragma unroll
    for (int n=0;n<2;n++){
      int col = wn*32 + n*16 + fr;
      float bv = bias[n0 + col];
      #pragma unroll
      for (int m=0;m<4;m++){
        #pragma unroll
        for (int i=0;i<4;i++){
          int row = wm*64 + m*16 + fg*4 + i;
          float v = acc[m][n][i] + bv;
          if (EPI==2){
            float e2 = __expf(-1.702f*v);
            v = v * __builtin_amdgcn_rcpf(1.f + e2);
          } else {
            v *= qscale;
          }
          unsigned pk = (unsigned)__builtin_amdgcn_cvt_pk_fp8_f32(v, v, 0, false);
          Cl[row*64 + col] = (unsigned char)(pk & 0xff);
        }
      }
    }
    __syncthreads();
    const int rr = tid >> 2, slot = tid & 3;
    #pragma unroll
    for (int it=0; it<2; ++it){
      int row = it*128 + rr;
      short8 v = *(const short8*)&Cl[row*64 + slot*16];
      *(short8*)&((unsigned char*)outp)[(size_t)(m0+row)*N + n0 + slot*16] = v;
    }
  } else if (EPI==5){
    // proj: y_bf16[pix] = x_fp32[pix] + v + bias
    const float* res = (const float*)resv;
    short* Cl = (short*)&As8[0][0][0];   // [256][64] bf16 (32 KB)
    #pragma unroll
    for (int n=0;n<2;n++){
      int col = wn*32 + n*16 + fr;
      float bv = bias[n0 + col];
      #pragma unroll
      for (int m=0;m<4;m++){
        #pragma unroll
        for (int i=0;i<4;i++){
          int row = wm*64 + m*16 + fg*4 + i;
          Cl[row*64 + col] = f2bf(acc[m][n][i] + bv);
        }
      }
    }
    __syncthreads();
    const int rr = tid >> 3, slot = tid & 7;
    #pragma unroll
    for (int it=0; it<4; ++it){
      int row = it*64 + rr;
      short8 v = *(const short8*)&Cl[row*64 + slot*8];
      int p = tok2pix(m0+row);
      size_t base = (size_t)p*CCH + n0 + slot*8;
      float4 x0 = *(const float4*)&res[base];
      float4 x1 = *(const float4*)&res[base+4];
      short8 o;
      o[0]=f2bf(x0.x+bf2f(v[0])); o[1]=f2bf(x0.y+bf2f(v[1]));
      o[2]=f2bf(x0.z+bf2f(v[2])); o[3]=f2bf(x0.w+bf2f(v[3]));
      o[4]=f2bf(x1.x+bf2f(v[4])); o[5]=f2bf(x1.y+bf2f(v[5]));
      o[6]=f2bf(x1.z+bf2f(v[6])); o[7]=f2bf(x1.w+bf2f(v[7]));
      *(short8*)&((short*)outp)[base] = o;
    }
  } else {
    // fc2: out_fp32[t] = y_bf16[t] + v + bias
    const short* resb = (const short*)resv;
    float* Cl = (float*)&As8[0][0][0];   // [256][64] fp32 (64 KB)
    #pragma unroll
    for (int n=0;n<2;n++){
      int col = wn*32 + n*16 + fr;
      float bv = bias[n0 + col];
      #pragma unroll
      for (int m=0;m<4;m++){
        #pragma unroll
        for (int i=0;i<4;i++){
          int row = wm*64 + m*16 + fg*4 + i;
          Cl[row*64 + col] = acc[m][n][i] + bv;
        }
      }
    }
    __syncthreads();
    const int rr = tid >> 4, slot = tid & 15;
    #pragma unroll
    for (int it=0; it<8; ++it){
      int row = it*32 + rr;
      float4 v = *(const float4*)&Cl[row*64 + slot*4];
      size_t idx = (size_t)(m0+row)*CCH + n0 + slot*4;
      short4 rv = *(const short4*)&resb[idx];
      v.x += bf2f(rv.x); v.y += bf2f(rv.y); v.z += bf2f(rv.z); v.w += bf2f(rv.w);
      *(float4*)&((float*)outp)[idx] = v;
    }
  }
}

// ---- all-fp8 MFMA windowed attention: block = window, wave w -> heads w,w+4,w+8.
__global__ __launch_bounds__(256) void attn_mfma8(const unsigned char* __restrict__ qkv8,
    const float* __restrict__ rbT, unsigned char* __restrict__ att8)
{
  __shared__ unsigned char Pl[4][64][72];
  __shared__ unsigned char Vt[4][32][72];
  __shared__ float lb[4][169];
  __shared__ int grp[64];
  const int wi = blockIdx.x;
  const int wid = threadIdx.x>>6, lane = threadIdx.x&63;
  const int fr = lane&15, fg = lane>>4;
  const int w = wi & 63, wh = w>>3, ww = w&7;
  if (threadIdx.x < 64){
    int t = threadIdx.x;
    int gv = 0;
    if (t < 49){
      int ai = t/7, aj = t%7;
      int hs = wh*7+ai, ws = ww*7+aj;
      int gh = hs<49?0:(hs<53?1:2);
      int gw = ws<49?0:(ws<53?1:2);
      gv = gh*3+gw;
    } else gv = -1;
    grp[t] = gv;
  }
  for (int t = lane; t < 288; t += 64)
    ((long*)&Vt[wid][0][0])[t] = 0;
  __syncthreads();   // the ONLY block barrier: grp visible to all waves
  const size_t tbase = (size_t)wi*49;

  for (int hi=0; hi<3; ++hi){
    const int h = hi*4 + wid;
    for (int t = lane; t < 169; t += 64) lb[wid][t] = rbT[h*169 + t];
    for (int t = lane; t < 196; t += 64){
      int j = t>>2, d0 = (t&3)*8;
      unsigned long vv = *(const unsigned long*)&qkv8[(tbase+j)*1152 + 768 + h*32 + d0];
      #pragma unroll
      for (int s=0;s<8;s++) Vt[wid][d0+s][j] = (unsigned char)(vv >> (8*s));
    }
    long aq[4], bk[4];
    #pragma unroll
    for (int m=0;m<4;m++){
      int r = m*16+fr;
      aq[m] = (r<49) ? *(const long*)&qkv8[(tbase+r)*1152       + h*32 + fg*8] : 0L;
      bk[m] = (r<49) ? *(const long*)&qkv8[(tbase+r)*1152 + 384 + h*32 + fg*8] : 0L;
    }

    floatx4 sc[4][4];
    #pragma unroll
    for (int m=0;m<4;m++)
      #pragma unroll
      for (int n=0;n<4;n++)
        sc[m][n] = __builtin_amdgcn_mfma_f32_16x16x32_fp8_fp8(aq[m], bk[n], (floatx4){0.f,0.f,0.f,0.f}, 0,0,0);

    int ciC[4], cjC[4], gC[4], cvC[4];
    #pragma unroll
    for (int n=0;n<4;n++){
      int c = n*16+fr;
      ciC[n] = c/7; cjC[n] = c - ciC[n]*7;
      gC[n] = grp[c]; cvC[n] = (c<49);
    }
    #pragma unroll
    for (int m=0;m<4;m++){
      #pragma unroll
      for (int i=0;i<4;i++){
        int r = m*16 + fg*4 + i;
        int rv = (r<49);
        int ri = r/7, rj = r - ri*7;
        int gr = grp[r];
        float mxv = -3e30f;
        #pragma unroll
        for (int n=0;n<4;n++){
          float s;
          if (rv && cvC[n]){
            int dr = ri - ciC[n] + 6, dc = rj - cjC[n] + 6;
            s = sc[m][n][i] + lb[wid][dr*13+dc];
            if (gr != gC[n]) s -= 100.f;
          } else s = -3e30f;
          sc[m][n][i] = s;
          mxv = fmaxf(mxv, s);
        }
        #pragma unroll
        for (int off=1;off<16;off<<=1) mxv = fmaxf(mxv, __shfl_xor(mxv, off));
        float sum = 0.f;
        #pragma unroll
        for (int n=0;n<4;n++){
          float e = __expf(sc[m][n][i]-mxv);
          sc[m][n][i] = e; sum += e;
        }
        #pragma unroll
        for (int off=1;off<16;off<<=1) sum += __shfl_xor(sum, off);
        float inv = 1.f/sum;
        #pragma unroll
        for (int n=0;n<4;n++){
          float p = sc[m][n][i]*inv;
          unsigned pk = (unsigned)__builtin_amdgcn_cvt_pk_fp8_f32(p, p, 0, false);
          Pl[wid][r][n*16+fr] = (unsigned char)(pk & 0xff);
        }
      }
    }

    long pa[4][2], vb[2][2];
    #pragma unroll
    for (int m=0;m<4;m++)
      #pragma unroll
      for (int ks=0;ks<2;ks++)
        pa[m][ks] = *(const long*)&Pl[wid][m*16+fr][ks*32+fg*8];
    #pragma unroll
    for (int n2=0;n2<2;n2++)
      #pragma unroll
      for (int ks=0;ks<2;ks++)
        vb[n2][ks] = *(const long*)&Vt[wid][n2*16+fr][ks*32+fg*8];
    floatx4 oc[4][2];
    #pragma unroll
    for (int m=0;m<4;m++)
      #pragma unroll
      for (int n2=0;n2<2;n2++){
        oc[m][n2] = (floatx4){0.f,0.f,0.f,0.f};
        #pragma unroll
        for (int ks=0;ks<2;ks++)
          oc[m][n2] = __builtin_amdgcn_mfma_f32_16x16x32_fp8_fp8(pa[m][ks], vb[n2][ks], oc[m][n2], 0,0,0);
      }
    #pragma unroll
    for (int m=0;m<4;m++){
      #pragma unroll
      for (int i=0;i<4;i++){
        int r = m*16 + fg*4 + i;
        if (r < 49){
          #pragma unroll
          for (int n2=0;n2<2;n2++){
            float v = oc[m][n2][i];
            unsigned pk = (unsigned)__builtin_amdgcn_cvt_pk_fp8_f32(v, v, 0, false);
            att8[(tbase+r)*384 + h*32 + n2*16 + fr] = (unsigned char)(pk & 0xff);
          }
        }
      }
    }
  }
}

extern "C" void kernel_launch(void* const* d_in, const int* in_sizes, int n_in,
                              void* d_out, int out_size, void* d_ws, size_t ws_size,
                              hipStream_t stream)
{
  const float* x      = (const float*)d_in[0];
  const float* n1g    = (const float*)d_in[1];
  const float* n1b    = (const float*)d_in[2];
  const float* qkv_w  = (const float*)d_in[3];
  const float* qkv_b  = (const float*)d_in[4];
  const float* relb   = (const float*)d_in[5];
  const float* proj_w = (const float*)d_in[6];
  const float* proj_b = (const float*)d_in[7];
  const float* n2g    = (const float*)d_in[8];
  const float* n2b    = (const float*)d_in[9];
  const float* fc1_w  = (const float*)d_in[10];
  const float* fc1_b  = (const float*)d_in[11];
  const float* fc2_w  = (const float*)d_in[12];
  const float* fc2_b  = (const float*)d_in[13];

  char* ws = (char*)d_ws;
  const size_t SZ_XW  = (size_t)NTOK*CCH*2;
  const size_t SZ_QKV = (size_t)NTOK*1152*2;
  const size_t SZ_ATT = SZ_XW;
  const size_t SZ_Y   = (size_t)NTOK*CCH*4;

  unsigned char* xw8  = (unsigned char*)(ws);            // [NTOK][384] fp8
  unsigned char* qkv8 = (unsigned char*)(ws + SZ_XW);    // [NTOK][1152] fp8
  unsigned char* att8 = (unsigned char*)(ws + SZ_XW + SZ_QKV);  // [NTOK][384] fp8
  short* y     = (short*)(ws + SZ_XW + SZ_QKV + SZ_ATT); // [NTOK][384] bf16 (pixel order)
  char*  wbuf  = ws + SZ_XW + SZ_QKV + SZ_ATT + SZ_Y;
  unsigned char* qkvW8 = (unsigned char*)wbuf;                     // [1152][384] fp8
  unsigned char* projW8= qkvW8 + (size_t)1152*384;                 // [384][384] fp8
  unsigned char* fc1W8 = projW8 + (size_t)384*384;                 // [1536][384] fp8
  unsigned char* fc2W8 = fc1W8 + (size_t)1536*384;                 // [384][1536] fp8
  float* rbT           = (float*)(fc2W8 + (size_t)384*1536);       // [12][169] fp32
  unsigned char* hbuf8 = qkv8;                           // [NTOK][1536] fp8 (reuses qkv8)
  unsigned char* hin8  = xw8;                            // [NTOK][384] fp8 (reuses xw8)

  wtconv8<<<dim3((384*1152+255)/256), dim3(256), 0, stream>>>(qkv_w, qkvW8, 384, 1152);
  wtconv8<<<dim3((384*384 +255)/256), dim3(256), 0, stream>>>(proj_w, projW8, 384, 384);
  wtconv8<<<dim3((384*1536+255)/256), dim3(256), 0, stream>>>(fc1_w, fc1W8, 384, 1536);
  wtconv8<<<dim3((1536*384+255)/256), dim3(256), 0, stream>>>(fc2_w, fc2W8, 1536, 384);
  rbt<<<dim3((169*12+255)/256), dim3(256), 0, stream>>>(relb, rbT);

  ln_fp8<1,0><<<dim3(NTOK/4), dim3(256), 0, stream>>>(x, n1g, n1b, xw8);
  gemmF8<4,384><<<dim3(18*196), dim3(512), 0, stream>>>(xw8, qkvW8, qkv_b, nullptr, qkv8, 1152, 18);
  attn_mfma8<<<dim3(NBATCH*NW), dim3(256), 0, stream>>>(qkv8, rbT, att8);
  gemmF8<5,384><<<dim3(6*196),  dim3(512), 0, stream>>>(att8, projW8, proj_b, x, y, 384, 6);
  ln_fp8<0,1><<<dim3(NTOK/4), dim3(256), 0, stream>>>(y, n2g, n2b, hin8);
  gemmF8<2,384><<<dim3(24*196), dim3(512), 0, stream>>>(hin8, fc1W8, fc1_b, nullptr, hbuf8, 1536, 24);
  gemmF8<3,1536><<<dim3(6*196), dim3(512), 0, stream>>>(hbuf8, fc2W8, fc2_b, y, (float*)d_out, 384, 6);
}